// Round 1
// baseline (8117.478 us; speedup 1.0000x reference)
//
#include <hip/hip_runtime.h>
#include <math.h>

// Problem constants (uniform scenes per reference)
#define NB 768      // batch = S*P
#define NS 32       // scenes
#define NP 24       // peds/scene
#define ED 64       // embedding dim E
#define HD 128      // hidden H
#define G4 512      // 4*H
#define BNKD 1024   // bottleneck
#define KM1 1152    // H + BNK
#define TSTEPS 12

// ---------------------------------------------------------------------------
// init: copy carries, dec_in0 = last_pos_rel @ W_se + b_se,
//       Wc = W_pse @ W_p1[:64]  (2x512),  bc = b_pse @ W_p1[:64] + b_p1
// ---------------------------------------------------------------------------
__global__ void init_kernel(const float* __restrict__ last_pos,
                            const float* __restrict__ last_pos_rel,
                            const float* __restrict__ h0,
                            const float* __restrict__ c0,
                            const float* __restrict__ W_se,
                            const float* __restrict__ b_se,
                            const float* __restrict__ W_pse,
                            const float* __restrict__ b_pse,
                            const float* __restrict__ W_p1,
                            const float* __restrict__ b_p1,
                            float* __restrict__ hcar, float* __restrict__ ccar,
                            float* __restrict__ din, float* __restrict__ lpos,
                            float* __restrict__ Wc, float* __restrict__ bc) {
  int stride = gridDim.x * blockDim.x;
  int idx0 = blockIdx.x * blockDim.x + threadIdx.x;
  for (int i = idx0; i < NB * HD; i += stride) { hcar[i] = h0[i]; ccar[i] = c0[i]; }
  for (int i = idx0; i < NB * 2; i += stride) lpos[i] = last_pos[i];
  for (int i = idx0; i < NB * ED; i += stride) {
    int r = i >> 6, e = i & 63;
    din[i] = b_se[e] + last_pos_rel[2 * r] * W_se[e]
                     + last_pos_rel[2 * r + 1] * W_se[ED + e];
  }
  for (int n = idx0; n < G4; n += stride) {
    float w0 = 0.f, w1 = 0.f, bb = b_p1[n];
    for (int e = 0; e < ED; ++e) {
      float wp = W_p1[e * G4 + n];
      w0 += W_pse[e] * wp;
      w1 += W_pse[ED + e] * wp;
      bb += b_pse[e] * wp;
    }
    Wc[n] = w0; Wc[G4 + n] = w1; bc[n] = bb;
  }
}

// ---------------------------------------------------------------------------
// step A: LSTM cell + rel_pos/curr_pos + dec_in_next + Hp1 = h_new @ W_p1[64:]
// 8 rows per block, 256 threads.
// ---------------------------------------------------------------------------
__global__ __launch_bounds__(256) void step_a(
    const float* __restrict__ hprev, const float* __restrict__ cprev,
    const float* __restrict__ din, const float* __restrict__ lpos_in,
    const float* __restrict__ W_ih, const float* __restrict__ b_ih,
    const float* __restrict__ W_hh, const float* __restrict__ b_hh,
    const float* __restrict__ W_hp, const float* __restrict__ b_hp,
    const float* __restrict__ W_se, const float* __restrict__ b_se,
    const float* __restrict__ W_p1,
    float* __restrict__ hn, float* __restrict__ cnext,
    float* __restrict__ dnext, float* __restrict__ lpos_out,
    float* __restrict__ Hp1, float* __restrict__ pred_out) {
  __shared__ float x[8][192];   // [din(64) | h(128)]
  __shared__ float gg[8][G4];
  __shared__ float hl[8][HD];
  __shared__ float rp[8][2];
  int t = threadIdx.x;
  int r0 = blockIdx.x * 8;

  for (int i = t; i < 8 * ED; i += 256) { int r = i >> 6, k = i & 63; x[r][k] = din[(r0 + r) * ED + k]; }
  for (int i = t; i < 8 * HD; i += 256) { int r = i >> 7, k = i & 127; x[r][ED + k] = hprev[(r0 + r) * HD + k]; }
  __syncthreads();

  // gates (N=512): cols t and t+256
  float acc[8][2];
#pragma unroll
  for (int r = 0; r < 8; ++r) { acc[r][0] = b_ih[t] + b_hh[t]; acc[r][1] = b_ih[t + 256] + b_hh[t + 256]; }
  for (int k = 0; k < ED; ++k) {
    float w0 = W_ih[k * G4 + t], w1 = W_ih[k * G4 + t + 256];
#pragma unroll
    for (int r = 0; r < 8; ++r) { float a = x[r][k]; acc[r][0] += a * w0; acc[r][1] += a * w1; }
  }
  for (int k = 0; k < HD; ++k) {
    float w0 = W_hh[k * G4 + t], w1 = W_hh[k * G4 + t + 256];
#pragma unroll
    for (int r = 0; r < 8; ++r) { float a = x[r][ED + k]; acc[r][0] += a * w0; acc[r][1] += a * w1; }
  }
#pragma unroll
  for (int r = 0; r < 8; ++r) { gg[r][t] = acc[r][0]; gg[r][t + 256] = acc[r][1]; }
  __syncthreads();

  // gate math (PyTorch order i,f,g,o)
  for (int i = t; i < 8 * HD; i += 256) {
    int r = i >> 7, k = i & 127;
    float ig = gg[r][k], fg = gg[r][HD + k], gz = gg[r][2 * HD + k], og = gg[r][3 * HD + k];
    float si = 1.f / (1.f + expf(-ig));
    float sf = 1.f / (1.f + expf(-fg));
    float so = 1.f / (1.f + expf(-og));
    float gt = tanhf(gz);
    float c = sf * cprev[(r0 + r) * HD + k] + si * gt;
    float h = so * tanhf(c);
    cnext[(r0 + r) * HD + k] = c;
    hn[(r0 + r) * HD + k] = h;
    hl[r][k] = h;
  }
  __syncthreads();

  // rel_pos / curr_pos / pred output
  if (t < 16) {
    int r = t >> 1, d = t & 1;
    float s = b_hp[d];
    for (int k = 0; k < HD; ++k) s += hl[r][k] * W_hp[k * 2 + d];
    rp[r][d] = s;
    pred_out[(r0 + r) * 2 + d] = s;
    lpos_out[(r0 + r) * 2 + d] = s + lpos_in[(r0 + r) * 2 + d];
  }
  __syncthreads();

  // dec_in_next = rel_pos @ W_se + b_se
  for (int i = t; i < 8 * ED; i += 256) {
    int r = i >> 6, e = i & 63;
    dnext[(r0 + r) * ED + e] = b_se[e] + rp[r][0] * W_se[e] + rp[r][1] * W_se[ED + e];
  }

  // Hp1 = h_new @ W_p1[64:192]  (N=512)
  float acc2[8][2];
#pragma unroll
  for (int r = 0; r < 8; ++r) { acc2[r][0] = 0.f; acc2[r][1] = 0.f; }
  for (int k = 0; k < HD; ++k) {
    float w0 = W_p1[(ED + k) * G4 + t], w1 = W_p1[(ED + k) * G4 + t + 256];
#pragma unroll
    for (int r = 0; r < 8; ++r) { float a = hl[r][k]; acc2[r][0] += a * w0; acc2[r][1] += a * w1; }
  }
#pragma unroll
  for (int r = 0; r < 8; ++r) {
    Hp1[(r0 + r) * G4 + t] = acc2[r][0];
    Hp1[(r0 + r) * G4 + t + 256] = acc2[r][1];
  }
}

// ---------------------------------------------------------------------------
// pool: one block per (scene, i). y1[j][k]=relu(rel2@Wc+bc+Hp1[j]) in LDS,
// then C = y1(24x512) @ W_p2(512x1024), pool_h[i][n] = max(0, max_j C[j][n]).
// ---------------------------------------------------------------------------
__global__ __launch_bounds__(256) void step_pool(
    const float* __restrict__ curr_pos, const float* __restrict__ Hp1,
    const float* __restrict__ Wc, const float* __restrict__ bc,
    const float* __restrict__ W_p2, const float* __restrict__ b_p2,
    float* __restrict__ pool_h) {
  __shared__ float y1[NP][G4];   // 48 KB
  __shared__ float ps[NP][2];
  int t = threadIdx.x;
  int blk = blockIdx.x;          // s*24 + i
  int s = blk / NP, i = blk % NP;
  if (t < NP * 2) ps[t >> 1][t & 1] = curr_pos[s * (NP * 2) + t];
  __syncthreads();
  float pix = ps[i][0], piy = ps[i][1];

  for (int idx = t; idx < NP * G4; idx += 256) {
    int j = idx >> 9, k = idx & 511;
    float rx = ps[j][0] - pix, ry = ps[j][1] - piy;
    float v = rx * Wc[k] + ry * Wc[G4 + k] + bc[k] + Hp1[(s * NP + j) * G4 + k];
    y1[j][k] = v > 0.f ? v : 0.f;
  }
  __syncthreads();

  // 4 consecutive cols per thread: n = 4t..4t+3
  float acc[NP][4];
#pragma unroll
  for (int j = 0; j < NP; ++j) { acc[j][0] = 0.f; acc[j][1] = 0.f; acc[j][2] = 0.f; acc[j][3] = 0.f; }
  const float4* W4 = (const float4*)W_p2;       // [512][256] of float4
  for (int k = 0; k < G4; k += 4) {
    float4 w0 = W4[(k + 0) * 256 + t];
    float4 w1 = W4[(k + 1) * 256 + t];
    float4 w2 = W4[(k + 2) * 256 + t];
    float4 w3 = W4[(k + 3) * 256 + t];
#pragma unroll
    for (int j = 0; j < NP; ++j) {
      float4 y = *(const float4*)&y1[j][k];
      acc[j][0] += y.x * w0.x + y.y * w1.x + y.z * w2.x + y.w * w3.x;
      acc[j][1] += y.x * w0.y + y.y * w1.y + y.z * w2.y + y.w * w3.y;
      acc[j][2] += y.x * w0.z + y.y * w1.z + y.z * w2.z + y.w * w3.z;
      acc[j][3] += y.x * w0.w + y.y * w1.w + y.z * w2.w + y.w * w3.w;
    }
  }
  float4 b = ((const float4*)b_p2)[t];
  float m0 = 0.f, m1 = 0.f, m2 = 0.f, m3 = 0.f;  // max_j relu(v) = max(0, max_j v)
#pragma unroll
  for (int j = 0; j < NP; ++j) {
    m0 = fmaxf(m0, acc[j][0] + b.x);
    m1 = fmaxf(m1, acc[j][1] + b.y);
    m2 = fmaxf(m2, acc[j][2] + b.z);
    m3 = fmaxf(m3, acc[j][3] + b.w);
  }
  float4 o; o.x = m0; o.y = m1; o.z = m2; o.w = m3;
  *(float4*)&pool_h[(s * NP + i) * BNKD + 4 * t] = o;
}

// ---------------------------------------------------------------------------
// mlp1: mh = relu([hn | pool_h] @ W_m1 + b_m1), 8 rows/block
// ---------------------------------------------------------------------------
__global__ __launch_bounds__(256) void step_mlp1(
    const float* __restrict__ hn, const float* __restrict__ ph,
    const float* __restrict__ W_m1, const float* __restrict__ b_m1,
    float* __restrict__ mh) {
  __shared__ float a[8][KM1];    // 36 KB
  int t = threadIdx.x, r0 = blockIdx.x * 8;
  for (int i = t; i < 8 * HD; i += 256) { int r = i >> 7, k = i & 127; a[r][k] = hn[(r0 + r) * HD + k]; }
  for (int i = t; i < 8 * BNKD; i += 256) { int r = i >> 10, k = i & 1023; a[r][HD + k] = ph[(r0 + r) * BNKD + k]; }
  __syncthreads();
  float acc[8][4];
#pragma unroll
  for (int r = 0; r < 8; ++r) { acc[r][0] = 0.f; acc[r][1] = 0.f; acc[r][2] = 0.f; acc[r][3] = 0.f; }
  const float4* W4 = (const float4*)W_m1;
  for (int k = 0; k < KM1; k += 4) {
    float4 w0 = W4[(k + 0) * 256 + t];
    float4 w1 = W4[(k + 1) * 256 + t];
    float4 w2 = W4[(k + 2) * 256 + t];
    float4 w3 = W4[(k + 3) * 256 + t];
#pragma unroll
    for (int r = 0; r < 8; ++r) {
      float4 av = *(const float4*)&a[r][k];
      acc[r][0] += av.x * w0.x + av.y * w1.x + av.z * w2.x + av.w * w3.x;
      acc[r][1] += av.x * w0.y + av.y * w1.y + av.z * w2.y + av.w * w3.y;
      acc[r][2] += av.x * w0.z + av.y * w1.z + av.z * w2.z + av.w * w3.z;
      acc[r][3] += av.x * w0.w + av.y * w1.w + av.z * w2.w + av.w * w3.w;
    }
  }
  float4 b = ((const float4*)b_m1)[t];
#pragma unroll
  for (int r = 0; r < 8; ++r) {
    float4 o;
    o.x = fmaxf(acc[r][0] + b.x, 0.f);
    o.y = fmaxf(acc[r][1] + b.y, 0.f);
    o.z = fmaxf(acc[r][2] + b.z, 0.f);
    o.w = fmaxf(acc[r][3] + b.w, 0.f);
    *(float4*)&mh[(r0 + r) * BNKD + 4 * t] = o;
  }
}

// ---------------------------------------------------------------------------
// mlp2: h_next = relu(mh @ W_m2 + b_m2), 8 rows/block, N=128
// ---------------------------------------------------------------------------
__global__ __launch_bounds__(256) void step_mlp2(
    const float* __restrict__ mh, const float* __restrict__ W_m2,
    const float* __restrict__ b_m2, float* __restrict__ hout) {
  __shared__ float a[8][BNKD];   // 32 KB
  int t = threadIdx.x, r0 = blockIdx.x * 8;
  for (int i = t; i < 8 * BNKD; i += 256) { int r = i >> 10, k = i & 1023; a[r][k] = mh[(r0 + r) * BNKD + k]; }
  __syncthreads();
  int n = t & 127, rh = t >> 7;   // 2 row-groups of 4
  float acc[4] = {0.f, 0.f, 0.f, 0.f};
  for (int k = 0; k < BNKD; k += 4) {
    float w0 = W_m2[(k + 0) * HD + n];
    float w1 = W_m2[(k + 1) * HD + n];
    float w2 = W_m2[(k + 2) * HD + n];
    float w3 = W_m2[(k + 3) * HD + n];
#pragma unroll
    for (int rr = 0; rr < 4; ++rr) {
      float4 av = *(const float4*)&a[rh * 4 + rr][k];
      acc[rr] += av.x * w0 + av.y * w1 + av.z * w2 + av.w * w3;
    }
  }
  float bb = b_m2[n];
#pragma unroll
  for (int rr = 0; rr < 4; ++rr)
    hout[(r0 + rh * 4 + rr) * HD + n] = fmaxf(acc[rr] + bb, 0.f);
}

// ---------------------------------------------------------------------------
extern "C" void kernel_launch(void* const* d_in, const int* in_sizes, int n_in,
                              void* d_out, int out_size, void* d_ws, size_t ws_size,
                              hipStream_t stream) {
  const float* last_pos     = (const float*)d_in[0];
  const float* last_pos_rel = (const float*)d_in[1];
  const float* h0   = (const float*)d_in[2];
  const float* c0   = (const float*)d_in[3];
  // d_in[4] seq_start_end (int32) — uniform scenes, unused
  const float* W_se = (const float*)d_in[5];
  const float* b_se = (const float*)d_in[6];
  const float* W_ih = (const float*)d_in[7];
  const float* b_ih = (const float*)d_in[8];
  const float* W_hh = (const float*)d_in[9];
  const float* b_hh = (const float*)d_in[10];
  const float* W_hp = (const float*)d_in[11];
  const float* b_hp = (const float*)d_in[12];
  const float* W_pse = (const float*)d_in[13];
  const float* b_pse = (const float*)d_in[14];
  const float* W_p1 = (const float*)d_in[15];
  const float* b_p1 = (const float*)d_in[16];
  const float* W_p2 = (const float*)d_in[17];
  const float* b_p2 = (const float*)d_in[18];
  const float* W_m1 = (const float*)d_in[19];
  const float* b_m1 = (const float*)d_in[20];
  const float* W_m2 = (const float*)d_in[21];
  const float* b_m2 = (const float*)d_in[22];

  float* ws = (float*)d_ws;
  float* hcar[2] = { ws,            ws + 98304 };
  float* ccar[2] = { ws + 196608,   ws + 294912 };
  float* din[2]  = { ws + 393216,   ws + 442368 };
  float* lposb[2]= { ws + 491520,   ws + 493056 };
  float* hn   = ws + 494592;
  float* Hp1  = ws + 592896;
  float* ph   = ws + 986112;
  float* mh   = ws + 1772544;
  float* Wc   = ws + 2558976;
  float* bc   = ws + 2560000;

  float* pred = (float*)d_out;

  init_kernel<<<128, 256, 0, stream>>>(last_pos, last_pos_rel, h0, c0,
                                       W_se, b_se, W_pse, b_pse, W_p1, b_p1,
                                       hcar[0], ccar[0], din[0], lposb[0], Wc, bc);

  for (int t = 0; t < TSTEPS; ++t) {
    int a = t & 1, b = (t + 1) & 1;
    step_a<<<NB / 8, 256, 0, stream>>>(hcar[a], ccar[a], din[a], lposb[a],
        W_ih, b_ih, W_hh, b_hh, W_hp, b_hp, W_se, b_se, W_p1,
        hn, ccar[b], din[b], lposb[b], Hp1, pred + t * NB * 2);
    step_pool<<<NB, 256, 0, stream>>>(lposb[b], Hp1, Wc, bc, W_p2, b_p2, ph);
    step_mlp1<<<NB / 8, 256, 0, stream>>>(hn, ph, W_m1, b_m1, mh);
    step_mlp2<<<NB / 8, 256, 0, stream>>>(mh, W_m2, b_m2, hcar[b]);
  }

  // final hidden state -> d_out[18432:]
  hipMemcpyAsync((float*)d_out + TSTEPS * NB * 2, hcar[0],
                 NB * HD * sizeof(float), hipMemcpyDeviceToDevice, stream);
}

// Round 3
// 2104.183 us; speedup vs baseline: 3.8578x; 3.8578x over previous
//
#include <hip/hip_runtime.h>
#include <math.h>

// Problem constants (uniform scenes per reference)
#define NB 768      // batch = S*P
#define NS 32       // scenes
#define NP 24       // peds/scene
#define ED 64       // embedding dim E
#define HD 128      // hidden H
#define G4 512      // 4*H
#define BNKD 1024   // bottleneck
#define KM1 1152    // H + BNK
#define TSTEPS 12

typedef __bf16 bf16x8 __attribute__((ext_vector_type(8)));
typedef float f32x4 __attribute__((ext_vector_type(4)));

__device__ __forceinline__ unsigned short f2bf(float f) {
  unsigned u = __float_as_uint(f);
  u = (u + 0x7FFFu + ((u >> 16) & 1u)) >> 16;   // RNE
  return (unsigned short)u;
}
__device__ __forceinline__ unsigned pack2bf(float a, float b) {
  return (unsigned)f2bf(a) | ((unsigned)f2bf(b) << 16);
}

// ---------------------------------------------------------------------------
// init: carries, dec_in0, folded pool-L1 weights (Wc = W_pse@W_p1[:64], bc),
// and bf16-transposed W2T[n][k] = W_p2[k][n], W1T[n][k] = W_m1[k][n].
// ---------------------------------------------------------------------------
__global__ void init_kernel(const float* __restrict__ last_pos,
                            const float* __restrict__ last_pos_rel,
                            const float* __restrict__ h0,
                            const float* __restrict__ c0,
                            const float* __restrict__ W_se,
                            const float* __restrict__ b_se,
                            const float* __restrict__ W_pse,
                            const float* __restrict__ b_pse,
                            const float* __restrict__ W_p1,
                            const float* __restrict__ b_p1,
                            const float* __restrict__ W_p2,
                            const float* __restrict__ W_m1,
                            float* __restrict__ hcar, float* __restrict__ ccar,
                            float* __restrict__ din, float* __restrict__ lpos,
                            float* __restrict__ Wc, float* __restrict__ bc,
                            unsigned short* __restrict__ W2T,
                            unsigned short* __restrict__ W1T) {
  int stride = gridDim.x * blockDim.x;
  int idx0 = blockIdx.x * blockDim.x + threadIdx.x;
  for (int i = idx0; i < NB * HD; i += stride) { hcar[i] = h0[i]; ccar[i] = c0[i]; }
  for (int i = idx0; i < NB * 2; i += stride) lpos[i] = last_pos[i];
  for (int i = idx0; i < NB * ED; i += stride) {
    int r = i >> 6, e = i & 63;
    din[i] = b_se[e] + last_pos_rel[2 * r] * W_se[e]
                     + last_pos_rel[2 * r + 1] * W_se[ED + e];
  }
  for (int n = idx0; n < G4; n += stride) {
    float w0 = 0.f, w1 = 0.f, bb = b_p1[n];
    for (int e = 0; e < ED; ++e) {
      float wp = W_p1[e * G4 + n];
      w0 += W_pse[e] * wp;
      w1 += W_pse[ED + e] * wp;
      bb += b_pse[e] * wp;
    }
    Wc[n] = w0; Wc[G4 + n] = w1; bc[n] = bb;
  }
  // W2T: 1024 rows x 512 k (bf16). idx -> (n, k0=8k chunk); lane-coalesced reads.
  for (int idx = idx0; idx < 1024 * 64; idx += stride) {
    int n = idx & 1023, k0 = (idx >> 10) << 3;
    unsigned pk0 = pack2bf(W_p2[(k0 + 0) * BNKD + n], W_p2[(k0 + 1) * BNKD + n]);
    unsigned pk1 = pack2bf(W_p2[(k0 + 2) * BNKD + n], W_p2[(k0 + 3) * BNKD + n]);
    unsigned pk2 = pack2bf(W_p2[(k0 + 4) * BNKD + n], W_p2[(k0 + 5) * BNKD + n]);
    unsigned pk3 = pack2bf(W_p2[(k0 + 6) * BNKD + n], W_p2[(k0 + 7) * BNKD + n]);
    *(uint4*)&W2T[n * G4 + k0] = make_uint4(pk0, pk1, pk2, pk3);
  }
  // W1T: 1024 rows x 1152 k (bf16)
  for (int idx = idx0; idx < 1024 * 144; idx += stride) {
    int n = idx & 1023, k0 = (idx >> 10) << 3;
    unsigned pk0 = pack2bf(W_m1[(k0 + 0) * BNKD + n], W_m1[(k0 + 1) * BNKD + n]);
    unsigned pk1 = pack2bf(W_m1[(k0 + 2) * BNKD + n], W_m1[(k0 + 3) * BNKD + n]);
    unsigned pk2 = pack2bf(W_m1[(k0 + 4) * BNKD + n], W_m1[(k0 + 5) * BNKD + n]);
    unsigned pk3 = pack2bf(W_m1[(k0 + 6) * BNKD + n], W_m1[(k0 + 7) * BNKD + n]);
    *(uint4*)&W1T[n * KM1 + k0] = make_uint4(pk0, pk1, pk2, pk3);
  }
}

// ---------------------------------------------------------------------------
// step A: LSTM cell + rel_pos/curr_pos + dec_in_next + Hp1 = h_new @ W_p1[64:]
// ---------------------------------------------------------------------------
__global__ __launch_bounds__(256) void step_a(
    const float* __restrict__ hprev, const float* __restrict__ cprev,
    const float* __restrict__ din, const float* __restrict__ lpos_in,
    const float* __restrict__ W_ih, const float* __restrict__ b_ih,
    const float* __restrict__ W_hh, const float* __restrict__ b_hh,
    const float* __restrict__ W_hp, const float* __restrict__ b_hp,
    const float* __restrict__ W_se, const float* __restrict__ b_se,
    const float* __restrict__ W_p1,
    float* __restrict__ hn, float* __restrict__ cnext,
    float* __restrict__ dnext, float* __restrict__ lpos_out,
    float* __restrict__ Hp1, float* __restrict__ pred_out) {
  __shared__ float x[8][192];   // [din(64) | h(128)]
  __shared__ float gg[8][G4];
  __shared__ float hl[8][HD];
  __shared__ float rp[8][2];
  int t = threadIdx.x;
  int r0 = blockIdx.x * 8;

  for (int i = t; i < 8 * ED; i += 256) { int r = i >> 6, k = i & 63; x[r][k] = din[(r0 + r) * ED + k]; }
  for (int i = t; i < 8 * HD; i += 256) { int r = i >> 7, k = i & 127; x[r][ED + k] = hprev[(r0 + r) * HD + k]; }
  __syncthreads();

  float acc[8][2];
#pragma unroll
  for (int r = 0; r < 8; ++r) { acc[r][0] = b_ih[t] + b_hh[t]; acc[r][1] = b_ih[t + 256] + b_hh[t + 256]; }
  for (int k = 0; k < ED; ++k) {
    float w0 = W_ih[k * G4 + t], w1 = W_ih[k * G4 + t + 256];
#pragma unroll
    for (int r = 0; r < 8; ++r) { float a = x[r][k]; acc[r][0] += a * w0; acc[r][1] += a * w1; }
  }
  for (int k = 0; k < HD; ++k) {
    float w0 = W_hh[k * G4 + t], w1 = W_hh[k * G4 + t + 256];
#pragma unroll
    for (int r = 0; r < 8; ++r) { float a = x[r][ED + k]; acc[r][0] += a * w0; acc[r][1] += a * w1; }
  }
#pragma unroll
  for (int r = 0; r < 8; ++r) { gg[r][t] = acc[r][0]; gg[r][t + 256] = acc[r][1]; }
  __syncthreads();

  for (int i = t; i < 8 * HD; i += 256) {
    int r = i >> 7, k = i & 127;
    float ig = gg[r][k], fg = gg[r][HD + k], gz = gg[r][2 * HD + k], og = gg[r][3 * HD + k];
    float si = 1.f / (1.f + expf(-ig));
    float sf = 1.f / (1.f + expf(-fg));
    float so = 1.f / (1.f + expf(-og));
    float gt = tanhf(gz);
    float c = sf * cprev[(r0 + r) * HD + k] + si * gt;
    float h = so * tanhf(c);
    cnext[(r0 + r) * HD + k] = c;
    hn[(r0 + r) * HD + k] = h;
    hl[r][k] = h;
  }
  __syncthreads();

  if (t < 16) {
    int r = t >> 1, d = t & 1;
    float s = b_hp[d];
    for (int k = 0; k < HD; ++k) s += hl[r][k] * W_hp[k * 2 + d];
    rp[r][d] = s;
    pred_out[(r0 + r) * 2 + d] = s;
    lpos_out[(r0 + r) * 2 + d] = s + lpos_in[(r0 + r) * 2 + d];
  }
  __syncthreads();

  for (int i = t; i < 8 * ED; i += 256) {
    int r = i >> 6, e = i & 63;
    dnext[(r0 + r) * ED + e] = b_se[e] + rp[r][0] * W_se[e] + rp[r][1] * W_se[ED + e];
  }

  float acc2[8][2];
#pragma unroll
  for (int r = 0; r < 8; ++r) { acc2[r][0] = 0.f; acc2[r][1] = 0.f; }
  for (int k = 0; k < HD; ++k) {
    float w0 = W_p1[(ED + k) * G4 + t], w1 = W_p1[(ED + k) * G4 + t + 256];
#pragma unroll
    for (int r = 0; r < 8; ++r) { float a = hl[r][k]; acc2[r][0] += a * w0; acc2[r][1] += a * w1; }
  }
#pragma unroll
  for (int r = 0; r < 8; ++r) {
    Hp1[(r0 + r) * G4 + t] = acc2[r][0];
    Hp1[(r0 + r) * G4 + t + 256] = acc2[r][1];
  }
}

// ---------------------------------------------------------------------------
// pool_mfma: per block: scene s, 4 ped-groups (96 = 4x24 rows), 128 cols.
// Y (A-operand) generated on the fly into LDS bf16; B from pre-transposed W2T.
// In-register max-over-j epilogue via shfl_xor. mfma 16x16x32 bf16.
// ---------------------------------------------------------------------------
__global__ __launch_bounds__(256) void pool_mfma(
    const float* __restrict__ curr_pos, const float* __restrict__ Hp1,
    const float* __restrict__ Wc, const float* __restrict__ bc,
    const unsigned short* __restrict__ W2T, const float* __restrict__ b_p2,
    float* __restrict__ pool_h) {
  __shared__ __align__(16) unsigned short Al[96 * 40];   // rows padded to 40 bf16
  __shared__ __align__(16) unsigned short Bl[128 * 40];
  __shared__ float psx[NP], psy[NP], bcs[G4], wc0[G4], wc1[G4];
  int t = threadIdx.x;
  int b = blockIdx.x;
  int s = b / 48, rem = b % 48;
  int i0 = (rem >> 3) * 4, n0 = (rem & 7) * 128;
  if (t < NP) {
    psx[t] = curr_pos[(s * NP + t) * 2];
    psy[t] = curr_pos[(s * NP + t) * 2 + 1];
  }
  for (int i = t; i < G4; i += 256) {
    bcs[i] = bc[i]; wc0[i] = Wc[i]; wc1[i] = Wc[G4 + i];
  }
  __syncthreads();

  int lane = t & 63, wid = t >> 6;
  int wm = wid >> 1, wn = wid & 1;
  int arow = lane & 15, ak = (lane >> 4) * 8;
  int kk2 = (t & 15) * 2;

  // Y-gen per-thread constants (k is the same for all 6 row-passes)
  const float* hrow[6];
  float rxv[6], ryv[6];
  int awr[6];
#pragma unroll
  for (int p = 0; p < 6; ++p) {
    int m = p * 16 + (t >> 4);
    int j = m % 24, g = m / 24;
    hrow[p] = Hp1 + (size_t)(s * NP + j) * G4 + kk2;
    rxv[p] = psx[j] - psx[i0 + g];
    ryv[p] = psy[j] - psy[i0 + g];
    awr[p] = m * 40 + kk2;
  }
  int aoff[3], boff[4];
#pragma unroll
  for (int f = 0; f < 3; ++f) aoff[f] = (wm * 48 + f * 16 + arow) * 40 + ak;
#pragma unroll
  for (int nf = 0; nf < 4; ++nf) boff[nf] = (wn * 64 + nf * 16 + arow) * 40 + ak;

  f32x4 acc[3][4];
#pragma unroll
  for (int f = 0; f < 3; ++f)
#pragma unroll
    for (int nf = 0; nf < 4; ++nf) acc[f][nf] = (f32x4){0.f, 0.f, 0.f, 0.f};

  int bn = t >> 2, bk = (t & 3) * 8;
  const unsigned short* w0p = W2T + (size_t)(n0 + bn) * G4 + bk;
  const unsigned short* w1p = W2T + (size_t)(n0 + bn + 64) * G4 + bk;
  int bw0 = bn * 40 + bk, bw1 = (bn + 64) * 40 + bk;

  for (int kt = 0; kt < 16; ++kt) {
    int k0 = kt * 32;
    int k = k0 + kk2;
    float c0v = bcs[k], c1v = bcs[k + 1];
    float a0v = wc0[k], a1v = wc0[k + 1];
    float e0v = wc1[k], e1v = wc1[k + 1];
#pragma unroll
    for (int p = 0; p < 6; ++p) {
      float2 hv = *(const float2*)(hrow[p] + k0);
      float v0 = fmaxf(c0v + a0v * rxv[p] + e0v * ryv[p] + hv.x, 0.f);
      float v1 = fmaxf(c1v + a1v * rxv[p] + e1v * ryv[p] + hv.y, 0.f);
      *(unsigned*)&Al[awr[p]] = pack2bf(v0, v1);
    }
    *(uint4*)&Bl[bw0] = *(const uint4*)(w0p + k0);
    *(uint4*)&Bl[bw1] = *(const uint4*)(w1p + k0);
    __syncthreads();
    bf16x8 af[3], bfr[4];
#pragma unroll
    for (int f = 0; f < 3; ++f) af[f] = *(const bf16x8*)&Al[aoff[f]];
#pragma unroll
    for (int nf = 0; nf < 4; ++nf) bfr[nf] = *(const bf16x8*)&Bl[boff[nf]];
#pragma unroll
    for (int f = 0; f < 3; ++f)
#pragma unroll
      for (int nf = 0; nf < 4; ++nf)
        acc[f][nf] = __builtin_amdgcn_mfma_f32_16x16x32_bf16(af[f], bfr[nf], acc[f][nf], 0, 0, 0);
    __syncthreads();
  }

  // epilogue: per wave, rows = peds (i0+2wm) [groupA: local rows 0-23] and
  // (i0+2wm+1) [groupB: 24-47]. C layout: row=(lane>>4)*4+reg, col=lane&15.
  int h = lane >> 4;
  int iA = s * NP + i0 + wm * 2;
#pragma unroll
  for (int nf = 0; nf < 4; ++nf) {
    f32x4 a0 = acc[0][nf], a1 = acc[1][nf], a2 = acc[2][nf];
    float v0 = fmaxf(fmaxf(a0[0], a0[1]), fmaxf(a0[2], a0[3]));
    float v1 = fmaxf(fmaxf(a1[0], a1[1]), fmaxf(a1[2], a1[3]));
    float v2 = fmaxf(fmaxf(a2[0], a2[1]), fmaxf(a2[2], a2[3]));
    v0 = fmaxf(v0, __shfl_xor(v0, 16));   // h01: rows 0-7 of frag; h23: 8-15
    v1 = fmaxf(v1, __shfl_xor(v1, 16));
    v2 = fmaxf(v2, __shfl_xor(v2, 16));
    float xx = (h < 2) ? fmaxf(v0, v1) : v0;    // A = frag0 all + frag1 lo
    xx = fmaxf(xx, __shfl_xor(xx, 32));
    float yy = (h >= 2) ? fmaxf(v2, v1) : v2;   // B = frag1 hi + frag2 all
    yy = fmaxf(yy, __shfl_xor(yy, 32));
    int col = n0 + wn * 64 + nf * 16 + (lane & 15);
    float bb = b_p2[col];
    xx = fmaxf(xx + bb, 0.f);
    yy = fmaxf(yy + bb, 0.f);
    if (h == 0) pool_h[(size_t)iA * BNKD + col] = xx;
    if (h == 1) pool_h[((size_t)iA + 1) * BNKD + col] = yy;
  }
}

// ---------------------------------------------------------------------------
// mlp1_mfma: mh = relu([hn|ph] @ W_m1 + b_m1). M-tile 32, N-tile 128, K=1152.
// ---------------------------------------------------------------------------
__global__ __launch_bounds__(256) void mlp1_mfma(
    const float* __restrict__ hn, const float* __restrict__ ph,
    const unsigned short* __restrict__ W1T, const float* __restrict__ b_m1,
    float* __restrict__ mh) {
  __shared__ __align__(16) unsigned short Al[32 * 40];
  __shared__ __align__(16) unsigned short Bl[128 * 40];
  int t = threadIdx.x;
  int b = blockIdx.x;
  int mt = b >> 3, nt = b & 7;
  int r0 = mt * 32, n0 = nt * 128;
  int lane = t & 63, wid = t >> 6;
  int wm = wid >> 1, wn = wid & 1;
  int arow = lane & 15, ak = (lane >> 4) * 8;
  int kk2 = (t & 15) * 2;

  f32x4 acc[4];
#pragma unroll
  for (int nf = 0; nf < 4; ++nf) acc[nf] = (f32x4){0.f, 0.f, 0.f, 0.f};
  int aoff = (wm * 16 + arow) * 40 + ak;
  int boff[4];
#pragma unroll
  for (int nf = 0; nf < 4; ++nf) boff[nf] = (wn * 64 + nf * 16 + arow) * 40 + ak;
  int bn = t >> 2, bk = (t & 3) * 8;
  const unsigned short* w0p = W1T + (size_t)(n0 + bn) * KM1 + bk;
  const unsigned short* w1p = W1T + (size_t)(n0 + bn + 64) * KM1 + bk;
  int bw0 = bn * 40 + bk, bw1 = (bn + 64) * 40 + bk;

  for (int kt = 0; kt < 36; ++kt) {
    int k0 = kt * 32;
#pragma unroll
    for (int p = 0; p < 2; ++p) {
      int m = p * 16 + (t >> 4);
      int kg = k0 + kk2;
      float2 v;
      if (k0 < HD) v = *(const float2*)&hn[(size_t)(r0 + m) * HD + kg];
      else         v = *(const float2*)&ph[(size_t)(r0 + m) * BNKD + (kg - HD)];
      *(unsigned*)&Al[m * 40 + kk2] = pack2bf(v.x, v.y);
    }
    *(uint4*)&Bl[bw0] = *(const uint4*)(w0p + k0);
    *(uint4*)&Bl[bw1] = *(const uint4*)(w1p + k0);
    __syncthreads();
    bf16x8 a = *(const bf16x8*)&Al[aoff];
#pragma unroll
    for (int nf = 0; nf < 4; ++nf) {
      bf16x8 bb = *(const bf16x8*)&Bl[boff[nf]];
      acc[nf] = __builtin_amdgcn_mfma_f32_16x16x32_bf16(a, bb, acc[nf], 0, 0, 0);
    }
    __syncthreads();
  }
#pragma unroll
  for (int nf = 0; nf < 4; ++nf) {
    int col = n0 + wn * 64 + nf * 16 + (lane & 15);
    float bb = b_m1[col];
#pragma unroll
    for (int rr = 0; rr < 4; ++rr) {
      int row = r0 + wm * 16 + (lane >> 4) * 4 + rr;
      mh[(size_t)row * BNKD + col] = fmaxf(acc[nf][rr] + bb, 0.f);
    }
  }
}

// ---------------------------------------------------------------------------
// mlp2: h_next = relu(mh @ W_m2 + b_m2), fp32 (0.2 GF/step)
// ---------------------------------------------------------------------------
__global__ __launch_bounds__(256) void step_mlp2(
    const float* __restrict__ mh, const float* __restrict__ W_m2,
    const float* __restrict__ b_m2, float* __restrict__ hout) {
  __shared__ float a[8][BNKD];
  int t = threadIdx.x, r0 = blockIdx.x * 8;
  for (int i = t; i < 8 * BNKD; i += 256) { int r = i >> 10, k = i & 1023; a[r][k] = mh[(r0 + r) * BNKD + k]; }
  __syncthreads();
  int n = t & 127, rh = t >> 7;
  float acc[4] = {0.f, 0.f, 0.f, 0.f};
  for (int k = 0; k < BNKD; k += 4) {
    float w0 = W_m2[(k + 0) * HD + n];
    float w1 = W_m2[(k + 1) * HD + n];
    float w2 = W_m2[(k + 2) * HD + n];
    float w3 = W_m2[(k + 3) * HD + n];
#pragma unroll
    for (int rr = 0; rr < 4; ++rr) {
      float4 av = *(const float4*)&a[rh * 4 + rr][k];
      acc[rr] += av.x * w0 + av.y * w1 + av.z * w2 + av.w * w3;
    }
  }
  float bb = b_m2[n];
#pragma unroll
  for (int rr = 0; rr < 4; ++rr)
    hout[(r0 + rh * 4 + rr) * HD + n] = fmaxf(acc[rr] + bb, 0.f);
}

// ---------------------------------------------------------------------------
extern "C" void kernel_launch(void* const* d_in, const int* in_sizes, int n_in,
                              void* d_out, int out_size, void* d_ws, size_t ws_size,
                              hipStream_t stream) {
  const float* last_pos     = (const float*)d_in[0];
  const float* last_pos_rel = (const float*)d_in[1];
  const float* h0   = (const float*)d_in[2];
  const float* c0   = (const float*)d_in[3];
  const float* W_se = (const float*)d_in[5];
  const float* b_se = (const float*)d_in[6];
  const float* W_ih = (const float*)d_in[7];
  const float* b_ih = (const float*)d_in[8];
  const float* W_hh = (const float*)d_in[9];
  const float* b_hh = (const float*)d_in[10];
  const float* W_hp = (const float*)d_in[11];
  const float* b_hp = (const float*)d_in[12];
  const float* W_pse = (const float*)d_in[13];
  const float* b_pse = (const float*)d_in[14];
  const float* W_p1 = (const float*)d_in[15];
  const float* b_p1 = (const float*)d_in[16];
  const float* W_p2 = (const float*)d_in[17];
  const float* b_p2 = (const float*)d_in[18];
  const float* W_m1 = (const float*)d_in[19];
  const float* b_m1 = (const float*)d_in[20];
  const float* W_m2 = (const float*)d_in[21];
  const float* b_m2 = (const float*)d_in[22];

  float* ws = (float*)d_ws;
  float* hcar[2] = { ws,            ws + 98304 };
  float* ccar[2] = { ws + 196608,   ws + 294912 };
  float* din[2]  = { ws + 393216,   ws + 442368 };
  float* lposb[2]= { ws + 491520,   ws + 493056 };
  float* hn   = ws + 494592;
  float* Hp1  = ws + 592896;
  float* ph   = ws + 986112;
  float* mh   = ws + 1772544;
  float* Wc   = ws + 2558976;
  float* bc   = ws + 2560000;
  unsigned short* W2T = (unsigned short*)(ws + 2560512);  // 1024x512 bf16
  unsigned short* W1T = (unsigned short*)(ws + 2822656);  // 1024x1152 bf16

  float* pred = (float*)d_out;

  init_kernel<<<128, 256, 0, stream>>>(last_pos, last_pos_rel, h0, c0,
                                       W_se, b_se, W_pse, b_pse, W_p1, b_p1,
                                       W_p2, W_m1,
                                       hcar[0], ccar[0], din[0], lposb[0],
                                       Wc, bc, W2T, W1T);

  for (int t = 0; t < TSTEPS; ++t) {
    int a = t & 1, b = (t + 1) & 1;
    step_a<<<NB / 8, 256, 0, stream>>>(hcar[a], ccar[a], din[a], lposb[a],
        W_ih, b_ih, W_hh, b_hh, W_hp, b_hp, W_se, b_se, W_p1,
        hn, ccar[b], din[b], lposb[b], Hp1, pred + t * NB * 2);
    pool_mfma<<<NS * 48, 256, 0, stream>>>(lposb[b], Hp1, Wc, bc, W2T, b_p2, ph);
    mlp1_mfma<<<192, 256, 0, stream>>>(hn, ph, W1T, b_m1, mh);
    step_mlp2<<<NB / 8, 256, 0, stream>>>(mh, W_m2, b_m2, hcar[b]);
  }

  hipMemcpyAsync((float*)d_out + TSTEPS * NB * 2, hcar[0],
                 NB * HD * sizeof(float), hipMemcpyDeviceToDevice, stream);
}

// Round 4
// 1389.276 us; speedup vs baseline: 5.8430x; 1.5146x over previous
//
#include <hip/hip_runtime.h>
#include <math.h>

// Problem constants (uniform scenes per reference)
#define NB 768      // batch = S*P
#define NS 32       // scenes
#define NP 24       // peds/scene
#define ED 64       // embedding dim E
#define HD 128      // hidden H
#define G4 512      // 4*H
#define BNKD 1024   // bottleneck
#define KM1 1152    // H + BNK
#define TSTEPS 12
#define AR 4        // rows per step_a block

typedef __bf16 bf16x8 __attribute__((ext_vector_type(8)));
typedef float f32x4 __attribute__((ext_vector_type(4)));
typedef unsigned short u16x8 __attribute__((ext_vector_type(8)));

__device__ __forceinline__ unsigned short f2bf(float f) {
  unsigned u = __float_as_uint(f);
  u = (u + 0x7FFFu + ((u >> 16) & 1u)) >> 16;   // RNE
  return (unsigned short)u;
}
__device__ __forceinline__ unsigned pack2bf(float a, float b) {
  return (unsigned)f2bf(a) | ((unsigned)f2bf(b) << 16);
}
__device__ __forceinline__ float bf2f(unsigned short h) {
  return __uint_as_float(((unsigned)h) << 16);
}

// ---------------------------------------------------------------------------
// init: carries, dec_in0, folded pool-L1 weights (Wc = W_pse@W_p1[:64], bc),
// bf16-transposed W2T[n][k]=W_p2[k][n], W1T[n][k]=W_m1[k][n], WmT[n][k]=W_m2[k][n]
// ---------------------------------------------------------------------------
__global__ void init_kernel(const float* __restrict__ last_pos,
                            const float* __restrict__ last_pos_rel,
                            const float* __restrict__ c0,
                            const float* __restrict__ W_se,
                            const float* __restrict__ b_se,
                            const float* __restrict__ W_pse,
                            const float* __restrict__ b_pse,
                            const float* __restrict__ W_p1,
                            const float* __restrict__ b_p1,
                            const float* __restrict__ W_p2,
                            const float* __restrict__ W_m1,
                            const float* __restrict__ W_m2,
                            float* __restrict__ ccar,
                            float* __restrict__ din, float* __restrict__ lpos,
                            float* __restrict__ Wc, float* __restrict__ bc,
                            unsigned short* __restrict__ W2T,
                            unsigned short* __restrict__ W1T,
                            unsigned short* __restrict__ WmT) {
  int stride = gridDim.x * blockDim.x;
  int idx0 = blockIdx.x * blockDim.x + threadIdx.x;
  for (int i = idx0; i < NB * HD; i += stride) ccar[i] = c0[i];
  for (int i = idx0; i < NB * 2; i += stride) lpos[i] = last_pos[i];
  for (int i = idx0; i < NB * ED; i += stride) {
    int r = i >> 6, e = i & 63;
    din[i] = b_se[e] + last_pos_rel[2 * r] * W_se[e]
                     + last_pos_rel[2 * r + 1] * W_se[ED + e];
  }
  for (int n = idx0; n < G4; n += stride) {
    float w0 = 0.f, w1 = 0.f, bb = b_p1[n];
    for (int e = 0; e < ED; ++e) {
      float wp = W_p1[e * G4 + n];
      w0 += W_pse[e] * wp;
      w1 += W_pse[ED + e] * wp;
      bb += b_pse[e] * wp;
    }
    Wc[n] = w0; Wc[G4 + n] = w1; bc[n] = bb;
  }
  // W2T: 1024 n x 512 k bf16
  for (int idx = idx0; idx < 1024 * 64; idx += stride) {
    int n = idx & 1023, k0 = (idx >> 10) << 3;
    unsigned pk0 = pack2bf(W_p2[(k0 + 0) * BNKD + n], W_p2[(k0 + 1) * BNKD + n]);
    unsigned pk1 = pack2bf(W_p2[(k0 + 2) * BNKD + n], W_p2[(k0 + 3) * BNKD + n]);
    unsigned pk2 = pack2bf(W_p2[(k0 + 4) * BNKD + n], W_p2[(k0 + 5) * BNKD + n]);
    unsigned pk3 = pack2bf(W_p2[(k0 + 6) * BNKD + n], W_p2[(k0 + 7) * BNKD + n]);
    *(uint4*)&W2T[n * G4 + k0] = make_uint4(pk0, pk1, pk2, pk3);
  }
  // W1T: 1024 n x 1152 k bf16
  for (int idx = idx0; idx < 1024 * 144; idx += stride) {
    int n = idx & 1023, k0 = (idx >> 10) << 3;
    unsigned pk0 = pack2bf(W_m1[(k0 + 0) * BNKD + n], W_m1[(k0 + 1) * BNKD + n]);
    unsigned pk1 = pack2bf(W_m1[(k0 + 2) * BNKD + n], W_m1[(k0 + 3) * BNKD + n]);
    unsigned pk2 = pack2bf(W_m1[(k0 + 4) * BNKD + n], W_m1[(k0 + 5) * BNKD + n]);
    unsigned pk3 = pack2bf(W_m1[(k0 + 6) * BNKD + n], W_m1[(k0 + 7) * BNKD + n]);
    *(uint4*)&W1T[n * KM1 + k0] = make_uint4(pk0, pk1, pk2, pk3);
  }
  // WmT: 128 n x 1024 k bf16   (W_m2 is [1024][128])
  for (int idx = idx0; idx < 128 * 128; idx += stride) {
    int n = idx & 127, k0 = (idx >> 7) << 3;
    unsigned pk0 = pack2bf(W_m2[(k0 + 0) * HD + n], W_m2[(k0 + 1) * HD + n]);
    unsigned pk1 = pack2bf(W_m2[(k0 + 2) * HD + n], W_m2[(k0 + 3) * HD + n]);
    unsigned pk2 = pack2bf(W_m2[(k0 + 4) * HD + n], W_m2[(k0 + 5) * HD + n]);
    unsigned pk3 = pack2bf(W_m2[(k0 + 6) * HD + n], W_m2[(k0 + 7) * HD + n]);
    *(uint4*)&WmT[n * BNKD + k0] = make_uint4(pk0, pk1, pk2, pk3);
  }
}

// ---------------------------------------------------------------------------
// step A: LSTM cell (h read = relu(hacc_prev) unless first step) + rel/curr pos
// + dec_in_next + Hp1 = h_new @ W_p1[64:] + bc  + hacc_next init = b_m2.
// 4 rows/block, grid 192.
// ---------------------------------------------------------------------------
__global__ __launch_bounds__(256) void step_a(
    const float* __restrict__ hprev, const float* __restrict__ cprev,
    const float* __restrict__ din, const float* __restrict__ lpos_in,
    const float* __restrict__ W_ih, const float* __restrict__ b_ih,
    const float* __restrict__ W_hh, const float* __restrict__ b_hh,
    const float* __restrict__ W_hp, const float* __restrict__ b_hp,
    const float* __restrict__ W_se, const float* __restrict__ b_se,
    const float* __restrict__ W_p1, const float* __restrict__ bc,
    const float* __restrict__ b_m2,
    float* __restrict__ hn, float* __restrict__ cnext,
    float* __restrict__ dnext, float* __restrict__ lpos_out,
    float* __restrict__ Hp1, float* __restrict__ pred_out,
    float* __restrict__ hacc_next, int relu_in) {
  __shared__ float x[AR][192];   // [din(64) | h(128)]
  __shared__ float gg[AR][G4];
  __shared__ float hl[AR][HD];
  __shared__ float rp[AR][2];
  int t = threadIdx.x;
  int r0 = blockIdx.x * AR;

  for (int i = t; i < AR * ED; i += 256) { int r = i >> 6, k = i & 63; x[r][k] = din[(r0 + r) * ED + k]; }
  for (int i = t; i < AR * HD; i += 256) {
    int r = i >> 7, k = i & 127;
    float v = hprev[(r0 + r) * HD + k];
    if (relu_in) v = fmaxf(v, 0.f);
    x[r][ED + k] = v;
    hacc_next[(r0 + r) * HD + k] = b_m2[k];   // bias-init mlp2 accumulator
  }
  __syncthreads();

  float acc[AR][2];
#pragma unroll
  for (int r = 0; r < AR; ++r) { acc[r][0] = b_ih[t] + b_hh[t]; acc[r][1] = b_ih[t + 256] + b_hh[t + 256]; }
  for (int k = 0; k < ED; ++k) {
    float w0 = W_ih[k * G4 + t], w1 = W_ih[k * G4 + t + 256];
#pragma unroll
    for (int r = 0; r < AR; ++r) { float a = x[r][k]; acc[r][0] += a * w0; acc[r][1] += a * w1; }
  }
  for (int k = 0; k < HD; ++k) {
    float w0 = W_hh[k * G4 + t], w1 = W_hh[k * G4 + t + 256];
#pragma unroll
    for (int r = 0; r < AR; ++r) { float a = x[r][ED + k]; acc[r][0] += a * w0; acc[r][1] += a * w1; }
  }
#pragma unroll
  for (int r = 0; r < AR; ++r) { gg[r][t] = acc[r][0]; gg[r][t + 256] = acc[r][1]; }
  __syncthreads();

  for (int i = t; i < AR * HD; i += 256) {
    int r = i >> 7, k = i & 127;
    float ig = gg[r][k], fg = gg[r][HD + k], gz = gg[r][2 * HD + k], og = gg[r][3 * HD + k];
    float si = 1.f / (1.f + expf(-ig));
    float sf = 1.f / (1.f + expf(-fg));
    float so = 1.f / (1.f + expf(-og));
    float gt = tanhf(gz);
    float c = sf * cprev[(r0 + r) * HD + k] + si * gt;
    float h = so * tanhf(c);
    cnext[(r0 + r) * HD + k] = c;
    hn[(r0 + r) * HD + k] = h;
    hl[r][k] = h;
  }
  __syncthreads();

  if (t < AR * 2) {
    int r = t >> 1, d = t & 1;
    float s = b_hp[d];
    for (int k = 0; k < HD; ++k) s += hl[r][k] * W_hp[k * 2 + d];
    rp[r][d] = s;
    pred_out[(r0 + r) * 2 + d] = s;
    lpos_out[(r0 + r) * 2 + d] = s + lpos_in[(r0 + r) * 2 + d];
  }
  __syncthreads();

  for (int i = t; i < AR * ED; i += 256) {
    int r = i >> 6, e = i & 63;
    dnext[(r0 + r) * ED + e] = b_se[e] + rp[r][0] * W_se[e] + rp[r][1] * W_se[ED + e];
  }

  // Hp1 = h_new @ W_p1[64:192] + bc   (bc folded here)
  float bc0 = bc[t], bc1 = bc[t + 256];
  float acc2[AR][2];
#pragma unroll
  for (int r = 0; r < AR; ++r) { acc2[r][0] = bc0; acc2[r][1] = bc1; }
  for (int k = 0; k < HD; ++k) {
    float w0 = W_p1[(ED + k) * G4 + t], w1 = W_p1[(ED + k) * G4 + t + 256];
#pragma unroll
    for (int r = 0; r < AR; ++r) { float a = hl[r][k]; acc2[r][0] += a * w0; acc2[r][1] += a * w1; }
  }
#pragma unroll
  for (int r = 0; r < AR; ++r) {
    Hp1[(r0 + r) * G4 + t] = acc2[r][0];
    Hp1[(r0 + r) * G4 + t + 256] = acc2[r][1];
  }
}

// ---------------------------------------------------------------------------
// pool_mfma v2: block = (scene, i-pair, n-half). M=48 (2 peds x 24 j), N=512.
// 4 waves split by N only; Y generated once into double-buffered LDS slice
// (one barrier per k-step); B-frags direct from L2-resident W2T.
// ---------------------------------------------------------------------------
__global__ __launch_bounds__(256, 2) void pool_mfma(
    const float* __restrict__ curr_pos, const float* __restrict__ Hp1,
    const float* __restrict__ Wc,
    const unsigned short* __restrict__ W2T, const float* __restrict__ b_p2,
    float* __restrict__ pool_h) {
  __shared__ __align__(16) unsigned short Al[2][48 * 40];  // rows padded to 40
  __shared__ float psx[NP], psy[NP], wc0[G4], wc1[G4];
  int t = threadIdx.x;
  int b = blockIdx.x;              // 768 = 32 scenes * 12 ipairs * 2 nhalf
  int s = b / 24, rem = b % 24;
  int ip = rem >> 1, nh = rem & 1;
  if (t < NP) {
    psx[t] = curr_pos[(s * NP + t) * 2];
    psy[t] = curr_pos[(s * NP + t) * 2 + 1];
  }
  for (int i = t; i < G4; i += 256) { wc0[i] = Wc[i]; wc1[i] = Wc[G4 + i]; }
  __syncthreads();

  int lane = t & 63, wn = t >> 6;
  int arow = lane & 15, ak = (lane >> 4) * 8;
  int kk2 = (t & 15) * 2;

  // Y-gen: 3 rows per thread (m = p*16 + t>>4), same k-pair for all
  const float* hrow[3];
  float rxv[3], ryv[3];
  int awr[3];
#pragma unroll
  for (int p = 0; p < 3; ++p) {
    int m = p * 16 + (t >> 4);
    int j = m % 24, g = m / 24;
    hrow[p] = Hp1 + (size_t)(s * NP + j) * G4 + kk2;
    rxv[p] = psx[j] - psx[ip * 2 + g];
    ryv[p] = psy[j] - psy[ip * 2 + g];
    awr[p] = m * 40 + kk2;
  }
  int aoff[3];
#pragma unroll
  for (int f = 0; f < 3; ++f) aoff[f] = (f * 16 + arow) * 40 + ak;

  int n0 = nh * 512 + wn * 128;
  const unsigned short* bptr[8];
#pragma unroll
  for (int nf = 0; nf < 8; ++nf)
    bptr[nf] = W2T + (size_t)(n0 + nf * 16 + arow) * G4 + ak;

  f32x4 acc[3][8];
#pragma unroll
  for (int f = 0; f < 3; ++f)
#pragma unroll
    for (int nf = 0; nf < 8; ++nf) acc[f][nf] = (f32x4){0.f, 0.f, 0.f, 0.f};

  for (int kt = 0; kt < 16; ++kt) {
    int k0 = kt * 32;
    int k = k0 + kk2;
    // issue global loads early (u rows + B frags), overlap with Y-gen/barrier
    float2 hv0 = *(const float2*)(hrow[0] + k0);
    float2 hv1 = *(const float2*)(hrow[1] + k0);
    float2 hv2 = *(const float2*)(hrow[2] + k0);
    bf16x8 bfr[8];
#pragma unroll
    for (int nf = 0; nf < 8; ++nf) bfr[nf] = *(const bf16x8*)(bptr[nf] + k0);

    float a0 = wc0[k], a1 = wc0[k + 1];
    float e0 = wc1[k], e1 = wc1[k + 1];
    unsigned short* dst = Al[kt & 1];
    {
      float v0 = fmaxf(hv0.x + a0 * rxv[0] + e0 * ryv[0], 0.f);
      float v1 = fmaxf(hv0.y + a1 * rxv[0] + e1 * ryv[0], 0.f);
      *(unsigned*)&dst[awr[0]] = pack2bf(v0, v1);
      v0 = fmaxf(hv1.x + a0 * rxv[1] + e0 * ryv[1], 0.f);
      v1 = fmaxf(hv1.y + a1 * rxv[1] + e1 * ryv[1], 0.f);
      *(unsigned*)&dst[awr[1]] = pack2bf(v0, v1);
      v0 = fmaxf(hv2.x + a0 * rxv[2] + e0 * ryv[2], 0.f);
      v1 = fmaxf(hv2.y + a1 * rxv[2] + e1 * ryv[2], 0.f);
      *(unsigned*)&dst[awr[2]] = pack2bf(v0, v1);
    }
    __syncthreads();
    bf16x8 af[3];
#pragma unroll
    for (int f = 0; f < 3; ++f) af[f] = *(const bf16x8*)&dst[aoff[f]];
#pragma unroll
    for (int nf = 0; nf < 8; ++nf)
#pragma unroll
      for (int f = 0; f < 3; ++f)
        acc[f][nf] = __builtin_amdgcn_mfma_f32_16x16x32_bf16(af[f], bfr[nf], acc[f][nf], 0, 0, 0);
  }

  // epilogue: max over j per ped group. frag rows: f0=g0 j0-15,
  // f1 lo=g0 j16-23 / hi=g1 j0-7, f2=g1 j8-23. C: row=(lane>>4)*4+reg, col=lane&15.
  int h = lane >> 4;
  int iA = s * NP + ip * 2;
#pragma unroll
  for (int nf = 0; nf < 8; ++nf) {
    f32x4 a0 = acc[0][nf], a1 = acc[1][nf], a2 = acc[2][nf];
    float v0 = fmaxf(fmaxf(a0[0], a0[1]), fmaxf(a0[2], a0[3]));
    float v1 = fmaxf(fmaxf(a1[0], a1[1]), fmaxf(a1[2], a1[3]));
    float v2 = fmaxf(fmaxf(a2[0], a2[1]), fmaxf(a2[2], a2[3]));
    v0 = fmaxf(v0, __shfl_xor(v0, 16));
    v1 = fmaxf(v1, __shfl_xor(v1, 16));
    v2 = fmaxf(v2, __shfl_xor(v2, 16));
    float xx = (h < 2) ? fmaxf(v0, v1) : v0;    // g0 = f0 all + f1 lo
    xx = fmaxf(xx, __shfl_xor(xx, 32));
    float yy = (h >= 2) ? fmaxf(v2, v1) : v2;   // g1 = f1 hi + f2 all
    yy = fmaxf(yy, __shfl_xor(yy, 32));
    int col = n0 + nf * 16 + (lane & 15);
    float bb = b_p2[col];
    xx = fmaxf(xx + bb, 0.f);
    yy = fmaxf(yy + bb, 0.f);
    if (h == 0) pool_h[(size_t)iA * BNKD + col] = xx;
    if (h == 1) pool_h[((size_t)iA + 1) * BNKD + col] = yy;
  }
}

// ---------------------------------------------------------------------------
// mlp1_fused: stage1 mh_tile = relu([hn|ph] @ W_m1 + b_m1) (32x128, regs),
// stage2 hacc += mh_tile @ W_m2[n0:n0+128, :] via bf16 hi+lo MFMA + atomicAdd.
// Stage 1 has no LDS/barriers: A converted in-register from global, B direct.
// ---------------------------------------------------------------------------
__global__ __launch_bounds__(256) void mlp1_fused(
    const float* __restrict__ hn, const float* __restrict__ ph,
    const unsigned short* __restrict__ W1T, const float* __restrict__ b_m1,
    const unsigned short* __restrict__ WmT, float* __restrict__ hacc) {
  __shared__ __align__(16) float Pl[32][132];
  int t = threadIdx.x, b = blockIdx.x;   // 192 = 24 mt * 8 nt
  int mt = b >> 3, nt = b & 7;
  int r0 = mt * 32, n0 = nt * 128;
  int lane = t & 63, wid = t >> 6, wm = wid >> 1, wn = wid & 1;
  int arow = lane & 15, ak = (lane >> 4) * 8;
  int h = lane >> 4;

  f32x4 acc0[4];
#pragma unroll
  for (int nf = 0; nf < 4; ++nf) acc0[nf] = (f32x4){0.f, 0.f, 0.f, 0.f};
  int mrow = r0 + wm * 16 + arow;
  const unsigned short* bp[4];
#pragma unroll
  for (int nf = 0; nf < 4; ++nf)
    bp[nf] = W1T + (size_t)(n0 + wn * 64 + nf * 16 + arow) * KM1 + ak;
  const float* arow_h = hn + (size_t)mrow * HD;
  const float* arow_p = ph + (size_t)mrow * BNKD - HD;  // biased so [kg] works

  for (int kt = 0; kt < 36; ++kt) {
    int kg = kt * 32 + ak;
    const float* src = (kg < HD) ? arow_h : arow_p;
    float4 v0 = *(const float4*)&src[kg];
    float4 v1 = *(const float4*)&src[kg + 4];
    u16x8 ua;
    ua[0] = f2bf(v0.x); ua[1] = f2bf(v0.y); ua[2] = f2bf(v0.z); ua[3] = f2bf(v0.w);
    ua[4] = f2bf(v1.x); ua[5] = f2bf(v1.y); ua[6] = f2bf(v1.z); ua[7] = f2bf(v1.w);
    bf16x8 a = __builtin_bit_cast(bf16x8, ua);
#pragma unroll
    for (int nf = 0; nf < 4; ++nf) {
      bf16x8 bb = *(const bf16x8*)(bp[nf] + kt * 32);
      acc0[nf] = __builtin_amdgcn_mfma_f32_16x16x32_bf16(a, bb, acc0[nf], 0, 0, 0);
    }
  }

  // P = relu(acc0 + b_m1) -> LDS (fp32)
#pragma unroll
  for (int nf = 0; nf < 4; ++nf) {
    int colp = wn * 64 + nf * 16 + arow;
    float bb = b_m1[n0 + colp];
#pragma unroll
    for (int rr = 0; rr < 4; ++rr)
      Pl[wm * 16 + h * 4 + rr][colp] = fmaxf(acc0[nf][rr] + bb, 0.f);
  }
  __syncthreads();

  // stage 2: (32x128 P-tile) @ WmT[:, n0:n0+128]^T -> 32x128 partial of h
  f32x4 acc2[4];
#pragma unroll
  for (int nf = 0; nf < 4; ++nf) acc2[nf] = (f32x4){0.f, 0.f, 0.f, 0.f};
  const unsigned short* b2p[4];
#pragma unroll
  for (int nf = 0; nf < 4; ++nf)
    b2p[nf] = WmT + (size_t)(wn * 64 + nf * 16 + arow) * BNKD + n0 + ak;
  const float* prow = &Pl[wm * 16 + arow][0];

#pragma unroll
  for (int k2 = 0; k2 < 4; ++k2) {
    u16x8 uh, ul;
#pragma unroll
    for (int q = 0; q < 8; ++q) {
      float vv = prow[k2 * 32 + ak + q];
      unsigned short hh = f2bf(vv);
      uh[q] = hh;
      ul[q] = f2bf(vv - bf2f(hh));
    }
    bf16x8 ahi = __builtin_bit_cast(bf16x8, uh);
    bf16x8 alo = __builtin_bit_cast(bf16x8, ul);
#pragma unroll
    for (int nf = 0; nf < 4; ++nf) {
      bf16x8 bb = *(const bf16x8*)(b2p[nf] + k2 * 32);
      acc2[nf] = __builtin_amdgcn_mfma_f32_16x16x32_bf16(ahi, bb, acc2[nf], 0, 0, 0);
      acc2[nf] = __builtin_amdgcn_mfma_f32_16x16x32_bf16(alo, bb, acc2[nf], 0, 0, 0);
    }
  }
#pragma unroll
  for (int nf = 0; nf < 4; ++nf)
#pragma unroll
    for (int rr = 0; rr < 4; ++rr)
      atomicAdd(&hacc[(size_t)(r0 + wm * 16 + h * 4 + rr) * HD + wn * 64 + nf * 16 + arow],
                acc2[nf][rr]);
}

// ---------------------------------------------------------------------------
// final: h_fin = relu(hacc)
// ---------------------------------------------------------------------------
__global__ void final_h(const float* __restrict__ hacc, float* __restrict__ out) {
  int i = blockIdx.x * 256 + threadIdx.x;
  if (i < NB * HD) out[i] = fmaxf(hacc[i], 0.f);
}

// ---------------------------------------------------------------------------
extern "C" void kernel_launch(void* const* d_in, const int* in_sizes, int n_in,
                              void* d_out, int out_size, void* d_ws, size_t ws_size,
                              hipStream_t stream) {
  const float* last_pos     = (const float*)d_in[0];
  const float* last_pos_rel = (const float*)d_in[1];
  const float* h0   = (const float*)d_in[2];
  const float* c0   = (const float*)d_in[3];
  const float* W_se = (const float*)d_in[5];
  const float* b_se = (const float*)d_in[6];
  const float* W_ih = (const float*)d_in[7];
  const float* b_ih = (const float*)d_in[8];
  const float* W_hh = (const float*)d_in[9];
  const float* b_hh = (const float*)d_in[10];
  const float* W_hp = (const float*)d_in[11];
  const float* b_hp = (const float*)d_in[12];
  const float* W_pse = (const float*)d_in[13];
  const float* b_pse = (const float*)d_in[14];
  const float* W_p1 = (const float*)d_in[15];
  const float* b_p1 = (const float*)d_in[16];
  const float* W_p2 = (const float*)d_in[17];
  const float* b_p2 = (const float*)d_in[18];
  const float* W_m1 = (const float*)d_in[19];
  const float* b_m1 = (const float*)d_in[20];
  const float* W_m2 = (const float*)d_in[21];
  const float* b_m2 = (const float*)d_in[22];

  float* ws = (float*)d_ws;
  float* hacc[2]  = { ws,           ws + 98304 };
  float* ccar[2]  = { ws + 196608,  ws + 294912 };
  float* din[2]   = { ws + 393216,  ws + 442368 };
  float* lposb[2] = { ws + 491520,  ws + 493056 };
  float* hn   = ws + 494592;
  float* Hp1  = ws + 592896;
  float* ph   = ws + 986112;
  float* Wc   = ws + 1772544;
  float* bc   = ws + 1773568;
  unsigned short* W2T = (unsigned short*)(ws + 1774080);  // 1024x512 bf16
  unsigned short* W1T = (unsigned short*)(ws + 2036224);  // 1024x1152 bf16
  unsigned short* WmT = (unsigned short*)(ws + 2626048);  // 128x1024 bf16

  float* pred = (float*)d_out;

  init_kernel<<<128, 256, 0, stream>>>(last_pos, last_pos_rel, c0,
                                       W_se, b_se, W_pse, b_pse, W_p1, b_p1,
                                       W_p2, W_m1, W_m2,
                                       ccar[0], din[0], lposb[0],
                                       Wc, bc, W2T, W1T, WmT);

  for (int t = 0; t < TSTEPS; ++t) {
    int a = t & 1, b = (t + 1) & 1;
    step_a<<<NB / AR, 256, 0, stream>>>(
        t == 0 ? h0 : hacc[a], ccar[a], din[a], lposb[a],
        W_ih, b_ih, W_hh, b_hh, W_hp, b_hp, W_se, b_se, W_p1, bc, b_m2,
        hn, ccar[b], din[b], lposb[b], Hp1, pred + t * NB * 2,
        hacc[b], t == 0 ? 0 : 1);
    pool_mfma<<<NS * 24, 256, 0, stream>>>(lposb[b], Hp1, Wc, W2T, b_p2, ph);
    mlp1_fused<<<192, 256, 0, stream>>>(hn, ph, W1T, b_m1, WmT, hacc[b]);
  }

  final_h<<<384, 256, 0, stream>>>(hacc[0], (float*)d_out + TSTEPS * NB * 2);
}